// Round 1
// baseline (502.661 us; speedup 1.0000x reference)
//
#include <hip/hip_runtime.h>
#include <cstdint>
#include <cstddef>

// Sizes fixed by the problem.
#define BTOK 1024
#define DDIM 1024
#define EEXP 16
#define HDIM 2048
#define ODIM 1024

typedef __bf16 bh;
typedef bh bh8 __attribute__((ext_vector_type(8)));
typedef bh bh4 __attribute__((ext_vector_type(4)));
typedef float fx4 __attribute__((ext_vector_type(4)));

__device__ __forceinline__ void gload16(const void* g, void* l) {
  // async global->LDS, 16B per lane; LDS dest is wave-uniform base + lane*16
  __builtin_amdgcn_global_load_lds(
      (const __attribute__((address_space(1))) void*)g,
      (__attribute__((address_space(3))) void*)l, 16, 0, 0);
}

// ---------------- transpose + fp32->bf16 convert ----------------
// in: [E][R][C] fp32 (C contiguous) -> out: [E][C][R] bf16
__global__ __launch_bounds__(256) void k_tcvt(const float* __restrict__ in,
                                              bh* __restrict__ out, int R, int C) {
  const int e = blockIdx.z;
  const int r0 = blockIdx.y * 64, c0 = blockIdx.x * 64;
  const float* pin = in + (size_t)e * R * C;
  bh* pout = out + (size_t)e * R * C;
  __shared__ __align__(16) bh t[64 * 65];
  const int tid = threadIdx.x;
#pragma unroll
  for (int rep = 0; rep < 4; ++rep) {
    int task = rep * 256 + tid;
    int r = task >> 4, c4 = task & 15;
    fx4 v = *(const fx4*)(pin + (size_t)(r0 + r) * C + c0 + c4 * 4);
    int base = r * 65 + c4 * 4;
#pragma unroll
    for (int u = 0; u < 4; ++u) t[base + u] = (bh)v[u];
  }
  __syncthreads();
#pragma unroll
  for (int rep = 0; rep < 4; ++rep) {
    int task = rep * 256 + tid;
    int cc = task >> 4, g2 = task & 15;
    bh4 o;
#pragma unroll
    for (int u = 0; u < 4; ++u) o[u] = t[(g2 * 4 + u) * 65 + cc];
    *(bh4*)(pout + (size_t)(c0 + cc) * R + r0 + g2 * 4) = o;
  }
}

// ---------------- gating: one block per token ----------------
__global__ __launch_bounds__(256) void k_gating(
    const float* __restrict__ x, const float* __restrict__ wg,
    const float* __restrict__ wn, const float* __restrict__ nz,
    bh* __restrict__ xbf, unsigned* __restrict__ cnt,
    int* __restrict__ tok_buck, float* __restrict__ gate_buck,
    float* __restrict__ imp_part, float* __restrict__ load_part) {
  const int b = blockIdx.x, tid = threadIdx.x;
  __shared__ __align__(16) float xs[1024];
  __shared__ float part[32][9];
  __shared__ float vals[32];
  fx4 v = *(const fx4*)(x + (size_t)b * 1024 + tid * 4);
  *(fx4*)(xs + tid * 4) = v;
  bh4 xb;
#pragma unroll
  for (int u = 0; u < 4; ++u) xb[u] = (bh)v[u];
  *(bh4*)(xbf + (size_t)b * 1024 + tid * 4) = xb;
  __syncthreads();
  const int col = tid & 31, g = tid >> 5;
  const float* wp = ((col < 16) ? wg : wn) + (col & 15);
  float s = 0.f;
  for (int it = g * 128; it < g * 128 + 128; ++it) s += xs[it] * wp[it * 16];
  part[col][g] = s;
  __syncthreads();
  if (tid < 32) {
    float tsum = 0.f;
#pragma unroll
    for (int gg = 0; gg < 8; ++gg) tsum += part[tid][gg];
    vals[tid] = tsum;
  }
  __syncthreads();
  if (tid == 0) {
    float clean[16], sd[16], noisy[16];
#pragma unroll
    for (int e = 0; e < 16; ++e) {
      clean[e] = vals[e];
      float raw = vals[16 + e];
      float sp = fmaxf(raw, 0.f) + log1pf(expf(-fabsf(raw)));
      sd[e] = sp + 0.1f;
      noisy[e] = clean[e] + nz[b * 16 + e] * sd[e];
    }
    float tv[5]; int ti[5]; unsigned used = 0;
    for (int r = 0; r < 5; ++r) {
      float bst = -INFINITY; int bi = 0;
      for (int e = 0; e < 16; ++e)
        if (!((used >> e) & 1u) && noisy[e] > bst) { bst = noisy[e]; bi = e; }
      used |= 1u << bi; tv[r] = bst; ti[r] = bi;
    }
    float gts[4]; float se = 0.f;
#pragma unroll
    for (int k = 0; k < 4; ++k) { gts[k] = expf(tv[k] - tv[0]); se += gts[k]; }
#pragma unroll
    for (int k = 0; k < 4; ++k) gts[k] /= se;
    const float thr_in = tv[4], thr_out = tv[3];
    float imp[16];
#pragma unroll
    for (int e = 0; e < 16; ++e) imp[e] = 0.f;
    for (int k = 0; k < 4; ++k) imp[ti[k]] = gts[k];
    for (int e = 0; e < 16; ++e) imp_part[b * 16 + e] = imp[e];
    for (int e = 0; e < 16; ++e) {
      bool is_in = noisy[e] > thr_in;
      float z = (clean[e] - (is_in ? thr_in : thr_out)) / sd[e];
      load_part[b * 16 + e] = 0.5f * (1.f + erff(z * 0.70710678118654752f));
    }
    for (int k = 0; k < 4; ++k) {
      int ee = ti[k];
      unsigned p = atomicAdd(&cnt[ee], 1u);
      tok_buck[ee * 1024 + (int)p] = b;
      gate_buck[ee * 1024 + (int)p] = gts[k];
    }
  }
}

__device__ __forceinline__ float cv2_16(const float* v) {
  float m = 0.f;
  for (int i = 0; i < 16; ++i) m += v[i];
  m *= (1.f / 16.f);
  float var = 0.f;
  for (int i = 0; i < 16; ++i) { float d = v[i] - m; var += d * d; }
  var *= (1.f / 15.f);
  return var / (m * m + 1e-10f);
}

// ---------------- offsets + loss ----------------
__global__ __launch_bounds__(256) void k_finalize(
    const unsigned* __restrict__ cnt, unsigned* __restrict__ offs,
    const float* __restrict__ imp_part, const float* __restrict__ load_part,
    float* __restrict__ loss_out) {
  const int tid = threadIdx.x;
  __shared__ float red[256];
  __shared__ float impv[16], loadv[16];
  const int e = tid & 15, p = tid >> 4;
  float s = 0.f;
  for (int r = 0; r < 64; ++r) s += imp_part[((p * 64 + r) << 4) + e];
  red[tid] = s;
  __syncthreads();
  if (tid < 16) {
    float t = 0.f;
    for (int pp = 0; pp < 16; ++pp) t += red[pp * 16 + tid];
    impv[tid] = t;
  }
  __syncthreads();
  s = 0.f;
  for (int r = 0; r < 64; ++r) s += load_part[((p * 64 + r) << 4) + e];
  red[tid] = s;
  __syncthreads();
  if (tid < 16) {
    float t = 0.f;
    for (int pp = 0; pp < 16; ++pp) t += red[pp * 16 + tid];
    loadv[tid] = t;
  }
  __syncthreads();
  if (tid == 0) {
    unsigned o = 0;
    for (int ee = 0; ee < 16; ++ee) { offs[ee] = o; o += cnt[ee]; }
    loss_out[0] = (cv2_16(impv) + cv2_16(loadv)) * 1e-4f;
  }
}

// ---------------- GEMM1: h = relu(x @ W1[e] + b1[e]) for routed rows ----------------
// A = gathered bf16 x rows [<=128 x 1024] (k-contig), B = W1T[e] [2048][1024] (k-contig)
// Depth-3 prefetch pipeline: 4 LDS buffers, counted vmcnt, raw barriers.
__global__ __launch_bounds__(256) void k_gemm1(
    const bh* __restrict__ xbf, const bh* __restrict__ w1t,
    const float* __restrict__ b1, const int* __restrict__ tok_buck,
    const unsigned* __restrict__ cnt, const unsigned* __restrict__ offs,
    bh* __restrict__ hbf) {
  const int e = blockIdx.z, mt = blockIdx.y, nt = blockIdx.x;
  const int ne = (int)cnt[e];
  if (mt * 128 >= ne) return;
  __shared__ __align__(16) bh As[4][128 * 32];
  __shared__ __align__(16) bh Bs[4][128 * 32];
  const int tid = threadIdx.x;
  const int lane = tid & 63, wv = tid >> 6, wm = wv >> 1, wn_ = wv & 1;

  const bh* a_src[2]; const bh* b_src[2];
  int dst_off[2];
#pragma unroll
  for (int r = 0; r < 2; ++r) {
    int task = r * 256 + tid;
    int row = task >> 2, s = task & 3;
    int gm = mt * 128 + row; if (gm >= ne) gm = ne - 1;
    int tok = tok_buck[e * 1024 + gm];
    a_src[r] = xbf + (size_t)tok * 1024 + ((s ^ (row & 3)) << 3);
    b_src[r] = w1t + (size_t)e * (2048 * 1024) + (size_t)(nt * 128 + row) * 1024 +
               ((s ^ (row & 3)) << 3);
    dst_off[r] = (r * 256 + (wv << 6)) << 4;  // byte offset within one buffer
  }
  const int ln15 = lane & 15, q = lane >> 4;
  const int qs = ((q ^ (ln15 & 3)) << 3);
  int a_off[4], b_off[4];
#pragma unroll
  for (int i = 0; i < 4; ++i) {
    a_off[i] = (wm * 64 + i * 16 + ln15) * 32 + qs;
    b_off[i] = (wn_ * 64 + i * 16 + ln15) * 32 + qs;
  }
  fx4 zero = {0.f, 0.f, 0.f, 0.f};
  fx4 acc[4][4];
#pragma unroll
  for (int i = 0; i < 4; ++i)
#pragma unroll
    for (int j = 0; j < 4; ++j) acc[i][j] = zero;

  auto stage = [&](int qb, int kt) {
    const int ko = kt * 32;
#pragma unroll
    for (int r = 0; r < 2; ++r) {
      gload16(a_src[r] + ko, (char*)(&As[qb][0]) + dst_off[r]);
      gload16(b_src[r] + ko, (char*)(&Bs[qb][0]) + dst_off[r]);
    }
  };

  const int NT = 32;
  stage(0, 0); stage(1, 1); stage(2, 2);
  asm volatile("s_waitcnt vmcnt(8)" ::: "memory");  // tile 0 landed (own wave)
  __builtin_amdgcn_s_barrier();                     // all waves' tile 0 landed

  for (int t = 0; t < NT; ++t) {
    if (t + 3 < NT) stage((t + 3) & 3, t + 3);
    const bh* Ab = &As[t & 3][0];
    const bh* Bb = &Bs[t & 3][0];
    bh8 af[4], bfr[4];
#pragma unroll
    for (int i = 0; i < 4; ++i) af[i] = *(const bh8*)(Ab + a_off[i]);
#pragma unroll
    for (int i = 0; i < 4; ++i) bfr[i] = *(const bh8*)(Bb + b_off[i]);
#pragma unroll
    for (int i = 0; i < 4; ++i)
#pragma unroll
      for (int j = 0; j < 4; ++j)
        acc[i][j] = __builtin_amdgcn_mfma_f32_16x16x32_bf16(af[i], bfr[j], acc[i][j], 0, 0, 0);
    // tile t+1 must be resident before anyone reads it next iter; keep t+2/t+3 in flight.
    if (t + 3 < NT)      asm volatile("s_waitcnt vmcnt(8) lgkmcnt(0)" ::: "memory");
    else if (t + 2 < NT) asm volatile("s_waitcnt vmcnt(4) lgkmcnt(0)" ::: "memory");
    else if (t + 1 < NT) asm volatile("s_waitcnt vmcnt(0) lgkmcnt(0)" ::: "memory");
    if (t + 1 < NT) __builtin_amdgcn_s_barrier();
  }

  int nrows = ne - mt * 128; if (nrows > 128) nrows = 128;
  int jn[4]; float b1v[4];
#pragma unroll
  for (int j = 0; j < 4; ++j) {
    jn[j] = nt * 128 + wn_ * 64 + j * 16 + ln15;
    b1v[j] = b1[e * 2048 + jn[j]];
  }
  const int rowbase = (int)offs[e] + mt * 128;
#pragma unroll
  for (int i = 0; i < 4; ++i)
#pragma unroll
    for (int rr = 0; rr < 4; ++rr) {
      int ml = wm * 64 + i * 16 + q * 4 + rr;
      if (ml < nrows) {
        size_t ro = (size_t)(rowbase + ml) * 2048;
#pragma unroll
        for (int j = 0; j < 4; ++j) {
          float vv = acc[i][j][rr] + b1v[j];
          hbf[ro + jn[j]] = (bh)fmaxf(vv, 0.f);
        }
      }
    }
}

// ---------------- GEMM2: y += gate * exp(h @ W2[e] + b2[e]) ----------------
__global__ __launch_bounds__(256) void k_gemm2(
    const bh* __restrict__ hbf, const bh* __restrict__ w2t,
    const float* __restrict__ b2, const int* __restrict__ tok_buck,
    const float* __restrict__ gate_buck, const unsigned* __restrict__ cnt,
    const unsigned* __restrict__ offs, float* __restrict__ yv) {
  const int e = blockIdx.z, mt = blockIdx.y, nt = blockIdx.x;
  const int ne = (int)cnt[e];
  if (mt * 128 >= ne) return;
  __shared__ __align__(16) bh As[4][128 * 32];
  __shared__ __align__(16) bh Bs[4][128 * 32];
  const int tid = threadIdx.x;
  const int lane = tid & 63, wv = tid >> 6, wm = wv >> 1, wn_ = wv & 1;
  const int rowbase = (int)offs[e] + mt * 128;

  const bh* a_src[2]; const bh* b_src[2];
  int dst_off[2];
#pragma unroll
  for (int r = 0; r < 2; ++r) {
    int task = r * 256 + tid;
    int row = task >> 2, s = task & 3;
    a_src[r] = hbf + (size_t)(rowbase + row) * 2048 + ((s ^ (row & 3)) << 3);
    b_src[r] = w2t + (size_t)e * (1024 * 2048) + (size_t)(nt * 128 + row) * 2048 +
               ((s ^ (row & 3)) << 3);
    dst_off[r] = (r * 256 + (wv << 6)) << 4;
  }
  const int ln15 = lane & 15, q = lane >> 4;
  const int qs = ((q ^ (ln15 & 3)) << 3);
  int a_off[4], b_off[4];
#pragma unroll
  for (int i = 0; i < 4; ++i) {
    a_off[i] = (wm * 64 + i * 16 + ln15) * 32 + qs;
    b_off[i] = (wn_ * 64 + i * 16 + ln15) * 32 + qs;
  }
  fx4 zero = {0.f, 0.f, 0.f, 0.f};
  fx4 acc[4][4];
#pragma unroll
  for (int i = 0; i < 4; ++i)
#pragma unroll
    for (int j = 0; j < 4; ++j) acc[i][j] = zero;

  auto stage = [&](int qb, int kt) {
    const int ko = kt * 32;
#pragma unroll
    for (int r = 0; r < 2; ++r) {
      gload16(a_src[r] + ko, (char*)(&As[qb][0]) + dst_off[r]);
      gload16(b_src[r] + ko, (char*)(&Bs[qb][0]) + dst_off[r]);
    }
  };

  const int NT = 64;
  stage(0, 0); stage(1, 1); stage(2, 2);
  asm volatile("s_waitcnt vmcnt(8)" ::: "memory");
  __builtin_amdgcn_s_barrier();

  for (int t = 0; t < NT; ++t) {
    if (t + 3 < NT) stage((t + 3) & 3, t + 3);
    const bh* Ab = &As[t & 3][0];
    const bh* Bb = &Bs[t & 3][0];
    bh8 af[4], bfr[4];
#pragma unroll
    for (int i = 0; i < 4; ++i) af[i] = *(const bh8*)(Ab + a_off[i]);
#pragma unroll
    for (int i = 0; i < 4; ++i) bfr[i] = *(const bh8*)(Bb + b_off[i]);
#pragma unroll
    for (int i = 0; i < 4; ++i)
#pragma unroll
      for (int j = 0; j < 4; ++j)
        acc[i][j] = __builtin_amdgcn_mfma_f32_16x16x32_bf16(af[i], bfr[j], acc[i][j], 0, 0, 0);
    if (t + 3 < NT)      asm volatile("s_waitcnt vmcnt(8) lgkmcnt(0)" ::: "memory");
    else if (t + 2 < NT) asm volatile("s_waitcnt vmcnt(4) lgkmcnt(0)" ::: "memory");
    else if (t + 1 < NT) asm volatile("s_waitcnt vmcnt(0) lgkmcnt(0)" ::: "memory");
    if (t + 1 < NT) __builtin_amdgcn_s_barrier();
  }

  int nrows = ne - mt * 128; if (nrows > 128) nrows = 128;
  int on[4]; float b2v[4];
#pragma unroll
  for (int j = 0; j < 4; ++j) {
    on[j] = nt * 128 + wn_ * 64 + j * 16 + ln15;
    b2v[j] = b2[e * 1024 + on[j]];
  }
#pragma unroll
  for (int i = 0; i < 4; ++i)
#pragma unroll
    for (int rr = 0; rr < 4; ++rr) {
      int ml = wm * 64 + i * 16 + q * 4 + rr;
      if (ml < nrows) {
        int pos = mt * 128 + ml;
        int bt = tok_buck[e * 1024 + pos];
        float gg = gate_buck[e * 1024 + pos];
        float* yrow = yv + (size_t)bt * 1024;
#pragma unroll
        for (int j = 0; j < 4; ++j)
          atomicAdd(&yrow[on[j]], gg * expf(acc[i][j][rr] + b2v[j]));
      }
    }
}

// ---------------- final log ----------------
__global__ __launch_bounds__(256) void k_log(float* __restrict__ yv) {
  const int i = blockIdx.x * 256 + threadIdx.x;
  fx4* p = (fx4*)yv + i;
  fx4 v = *p;
#pragma unroll
  for (int c = 0; c < 4; ++c) {
    float w = v[c];
    if (w == 0.f) w = 2.2204460492503131e-16f;
    v[c] = logf(w);
  }
  *p = v;
}

extern "C" void kernel_launch(void* const* d_in, const int* in_sizes, int n_in,
                              void* d_out, int out_size, void* d_ws, size_t ws_size,
                              hipStream_t stream) {
  const float* x  = (const float*)d_in[0];
  const float* wg = (const float*)d_in[1];
  const float* wn = (const float*)d_in[2];
  const float* W1 = (const float*)d_in[3];
  const float* b1 = (const float*)d_in[4];
  const float* W2 = (const float*)d_in[5];
  const float* b2 = (const float*)d_in[6];
  const float* nz = (const float*)d_in[7];
  float* out = (float*)d_out;

  // workspace layout (bytes)
  char* ws = (char*)d_ws;
  unsigned* cnt      = (unsigned*)(ws + 0);          // 64 B
  unsigned* offs     = (unsigned*)(ws + 64);         // 64 B
  float*    imp_part = (float*)(ws + 256);           // 64 KB
  float*    load_part= (float*)(ws + 256 + 65536);   // 64 KB
  int*      tok_buck = (int*)(ws + 256 + 2 * 65536); // 64 KB
  float*    gate_buck= (float*)(ws + 256 + 3 * 65536); // 64 KB
  bh*       xbf      = (bh*)(ws + 262400);           // 2 MB
  bh*       hbf      = (bh*)(ws + 2359552);          // (4096+128)*2048*2 = 16.5 MiB
  bh*       w1t      = (bh*)(ws + 19661056);         // 64 MiB
  bh*       w2t      = (bh*)(ws + 86769920);         // 64 MiB
  const size_t needed = 153878784;
  if (ws_size < needed) {
    // sentinel: distinguishable failure mode (absmax ~48) if ws is too small
    hipMemsetAsync(d_out, 0x42, (size_t)out_size * 4, stream);
    return;
  }

  hipMemsetAsync(d_out, 0, (size_t)out_size * 4, stream);
  hipMemsetAsync(cnt, 0, 64, stream);

  // W1 [E][1024][2048] -> w1t [E][2048][1024]; W2 [E][2048][1024] -> w2t [E][1024][2048]
  k_tcvt<<<dim3(2048 / 64, 1024 / 64, 16), 256, 0, stream>>>(W1, w1t, 1024, 2048);
  k_tcvt<<<dim3(1024 / 64, 2048 / 64, 16), 256, 0, stream>>>(W2, w2t, 2048, 1024);
  k_gating<<<1024, 256, 0, stream>>>(x, wg, wn, nz, xbf, cnt, tok_buck, gate_buck,
                                     imp_part, load_part);
  k_finalize<<<1, 256, 0, stream>>>(cnt, offs, imp_part, load_part, out + (out_size - 1));
  k_gemm1<<<dim3(16, 8, 16), 256, 0, stream>>>(xbf, w1t, b1, tok_buck, cnt, offs, hbf);
  k_gemm2<<<dim3(8, 8, 16), 256, 0, stream>>>(hbf, w2t, b2, tok_buck, gate_buck, cnt, offs, out);
  k_log<<<1024, 256, 0, stream>>>(out);
}

// Round 2
// 470.570 us; speedup vs baseline: 1.0682x; 1.0682x over previous
//
#include <hip/hip_runtime.h>
#include <cstdint>
#include <cstddef>

// Sizes fixed by the problem.
#define BTOK 1024
#define DDIM 1024
#define EEXP 16
#define HDIM 2048
#define ODIM 1024

typedef __bf16 bh;
typedef bh bh8 __attribute__((ext_vector_type(8)));
typedef bh bh4 __attribute__((ext_vector_type(4)));
typedef float fx4 __attribute__((ext_vector_type(4)));

__device__ __forceinline__ void gload16(const void* g, void* l) {
  // async global->LDS, 16B per lane; LDS dest is wave-uniform base + lane*16
  __builtin_amdgcn_global_load_lds(
      (const __attribute__((address_space(1))) void*)g,
      (__attribute__((address_space(3))) void*)l, 16, 0, 0);
}

// ---------------- gating: one block per token ----------------
__global__ __launch_bounds__(256) void k_gating(
    const float* __restrict__ x, const float* __restrict__ wg,
    const float* __restrict__ wn, const float* __restrict__ nz,
    bh* __restrict__ xbf, unsigned* __restrict__ cnt,
    int* __restrict__ tok_buck, float* __restrict__ gate_buck,
    float* __restrict__ imp_part, float* __restrict__ load_part) {
  const int b = blockIdx.x, tid = threadIdx.x;
  __shared__ __align__(16) float xs[1024];
  __shared__ float part[32][9];
  __shared__ float vals[32];
  fx4 v = *(const fx4*)(x + (size_t)b * 1024 + tid * 4);
  *(fx4*)(xs + tid * 4) = v;
  bh4 xb;
#pragma unroll
  for (int u = 0; u < 4; ++u) xb[u] = (bh)v[u];
  *(bh4*)(xbf + (size_t)b * 1024 + tid * 4) = xb;
  __syncthreads();
  const int col = tid & 31, g = tid >> 5;
  const float* wp = ((col < 16) ? wg : wn) + (col & 15);
  float s = 0.f;
  for (int it = g * 128; it < g * 128 + 128; ++it) s += xs[it] * wp[it * 16];
  part[col][g] = s;
  __syncthreads();
  if (tid < 32) {
    float tsum = 0.f;
#pragma unroll
    for (int gg = 0; gg < 8; ++gg) tsum += part[tid][gg];
    vals[tid] = tsum;
  }
  __syncthreads();
  if (tid == 0) {
    float clean[16], sd[16], noisy[16];
#pragma unroll
    for (int e = 0; e < 16; ++e) {
      clean[e] = vals[e];
      float raw = vals[16 + e];
      float sp = fmaxf(raw, 0.f) + log1pf(expf(-fabsf(raw)));
      sd[e] = sp + 0.1f;
      noisy[e] = clean[e] + nz[b * 16 + e] * sd[e];
    }
    float tv[5]; int ti[5]; unsigned used = 0;
    for (int r = 0; r < 5; ++r) {
      float bst = -INFINITY; int bi = 0;
      for (int e = 0; e < 16; ++e)
        if (!((used >> e) & 1u) && noisy[e] > bst) { bst = noisy[e]; bi = e; }
      used |= 1u << bi; tv[r] = bst; ti[r] = bi;
    }
    float gts[4]; float se = 0.f;
#pragma unroll
    for (int k = 0; k < 4; ++k) { gts[k] = expf(tv[k] - tv[0]); se += gts[k]; }
#pragma unroll
    for (int k = 0; k < 4; ++k) gts[k] /= se;
    const float thr_in = tv[4], thr_out = tv[3];
    float imp[16];
#pragma unroll
    for (int e = 0; e < 16; ++e) imp[e] = 0.f;
    for (int k = 0; k < 4; ++k) imp[ti[k]] = gts[k];
    for (int e = 0; e < 16; ++e) imp_part[b * 16 + e] = imp[e];
    for (int e = 0; e < 16; ++e) {
      bool is_in = noisy[e] > thr_in;
      float z = (clean[e] - (is_in ? thr_in : thr_out)) / sd[e];
      load_part[b * 16 + e] = 0.5f * (1.f + erff(z * 0.70710678118654752f));
    }
    for (int k = 0; k < 4; ++k) {
      int ee = ti[k];
      unsigned p = atomicAdd(&cnt[ee], 1u);
      tok_buck[ee * 1024 + (int)p] = b;
      gate_buck[ee * 1024 + (int)p] = gts[k];
    }
  }
}

__device__ __forceinline__ float cv2_16(const float* v) {
  float m = 0.f;
  for (int i = 0; i < 16; ++i) m += v[i];
  m *= (1.f / 16.f);
  float var = 0.f;
  for (int i = 0; i < 16; ++i) { float d = v[i] - m; var += d * d; }
  var *= (1.f / 15.f);
  return var / (m * m + 1e-10f);
}

// ---------------- offsets + loss ----------------
__global__ __launch_bounds__(256) void k_finalize(
    const unsigned* __restrict__ cnt, unsigned* __restrict__ offs,
    const float* __restrict__ imp_part, const float* __restrict__ load_part,
    float* __restrict__ loss_out) {
  const int tid = threadIdx.x;
  __shared__ float red[256];
  __shared__ float impv[16], loadv[16];
  const int e = tid & 15, p = tid >> 4;
  float s = 0.f;
  for (int r = 0; r < 64; ++r) s += imp_part[((p * 64 + r) << 4) + e];
  red[tid] = s;
  __syncthreads();
  if (tid < 16) {
    float t = 0.f;
    for (int pp = 0; pp < 16; ++pp) t += red[pp * 16 + tid];
    impv[tid] = t;
  }
  __syncthreads();
  s = 0.f;
  for (int r = 0; r < 64; ++r) s += load_part[((p * 64 + r) << 4) + e];
  red[tid] = s;
  __syncthreads();
  if (tid < 16) {
    float t = 0.f;
    for (int pp = 0; pp < 16; ++pp) t += red[pp * 16 + tid];
    loadv[tid] = t;
  }
  __syncthreads();
  if (tid == 0) {
    unsigned o = 0;
    for (int ee = 0; ee < 16; ++ee) { offs[ee] = o; o += cnt[ee]; }
    loss_out[0] = (cv2_16(impv) + cv2_16(loadv)) * 1e-4f;
  }
}

// ======== shared GEMM staging/compute machinery (macros; locals per kernel) ========
// A: global_load_lds, linear LDS dest, XOR-pre-swizzled global source (verified path).
// B: reg-staged from native fp32 weights (fused transpose+convert):
//    16 coalesced dword loads/thread (lane->n), cvt to bf16, 2 conflict-free
//    ds_write_b128 into Bs layout [k-octet q'][n] (bh8 units: q'*128 + n).
// Schedule: ring-4 LDS buffers; at iter t head issue B(t+2)+A(t+3); at tail
// wait region-granular vmcnt(18) (completes head(t-1) = B(t+1)+A(t+2)),
// cvt+write B(t+1), lgkmcnt(0), barrier. vmcnt never drains to 0 mid-loop.

#define SBAR0() __builtin_amdgcn_sched_barrier(0)
#define WAITV(N) asm volatile("s_waitcnt vmcnt(" #N ")" ::: "memory")
#define WAITL() asm volatile("s_waitcnt lgkmcnt(0)" ::: "memory")

#define B_LOAD(SLOT, T) do {                                        \
  const float* bp_ = bsrc + (size_t)(T) * (32 * BRS);               \
  _Pragma("unroll") for (int kk_ = 0; kk_ < 16; ++kk_)              \
    br[SLOT][kk_] = bp_[(size_t)kk_ * BRS];                         \
} while (0)

#define A_STAGE(BUF, T) do {                                        \
  int ko_ = (T) * 32;                                               \
  gload16(a_src[0] + ko_, (char*)(&As[BUF][0]) + dst_off[0]);       \
  gload16(a_src[1] + ko_, (char*)(&As[BUF][0]) + dst_off[1]);       \
} while (0)

#define B_CVTW(SLOT, BUF) do {                                      \
  bh8 w0_, w1_;                                                     \
  _Pragma("unroll") for (int u_ = 0; u_ < 8; ++u_) {                \
    w0_[u_] = (bh)br[SLOT][u_]; w1_[u_] = (bh)br[SLOT][8 + u_]; }   \
  *(bh8*)(&Bs[BUF][(size_t)bq0 * 1024 + bn8]) = w0_;                \
  *(bh8*)(&Bs[BUF][(size_t)(bq0 + 1) * 1024 + bn8]) = w1_;          \
} while (0)

#define COMPUTE(BUF) do {                                           \
  bh8 af_[4], bf_[4];                                               \
  _Pragma("unroll") for (int i_ = 0; i_ < 4; ++i_)                  \
    af_[i_] = *(const bh8*)(&As[BUF][a_off[i_]]);                   \
  _Pragma("unroll") for (int i_ = 0; i_ < 4; ++i_)                  \
    bf_[i_] = *(const bh8*)(&Bs[BUF][(size_t)(q * 128 + wn_ * 64 + i_ * 16 + ln15) * 8]); \
  _Pragma("unroll") for (int i_ = 0; i_ < 4; ++i_)                  \
    _Pragma("unroll") for (int j_ = 0; j_ < 4; ++j_)                \
      acc[i_][j_] = __builtin_amdgcn_mfma_f32_16x16x32_bf16(af_[i_], bf_[j_], acc[i_][j_], 0, 0, 0); \
} while (0)

#define KSTEP_STD(T, K) do {                                        \
  B_LOAD(((K) + 2) & 3, (T) + 2);                                   \
  A_STAGE(((K) + 3) & 3, (T) + 3);                                  \
  SBAR0();                                                          \
  COMPUTE((K));                                                     \
  WAITV(18);                                                        \
  B_CVTW(((K) + 1) & 3, ((K) + 1) & 3);                             \
  WAITL();                                                          \
  __builtin_amdgcn_s_barrier();                                     \
} while (0)

#define KSTEP_T3(T, K) do {   /* t = NT-3: no A issue */            \
  B_LOAD(((K) + 2) & 3, (T) + 2);                                   \
  SBAR0();                                                          \
  COMPUTE((K));                                                     \
  WAITV(16);                                                        \
  B_CVTW(((K) + 1) & 3, ((K) + 1) & 3);                             \
  WAITL();                                                          \
  __builtin_amdgcn_s_barrier();                                     \
} while (0)

#define KSTEP_T2(K) do {      /* t = NT-2: no issues */             \
  COMPUTE((K));                                                     \
  WAITV(0);                                                         \
  B_CVTW(((K) + 1) & 3, ((K) + 1) & 3);                             \
  WAITL();                                                          \
  __builtin_amdgcn_s_barrier();                                     \
} while (0)

#define KSTEP_LAST(K) do { COMPUTE((K)); } while (0)

#define GEMM_PROLOGUE() do {                                        \
  B_LOAD(0, 0); A_STAGE(0, 0); SBAR0();                             \
  B_LOAD(1, 1); A_STAGE(1, 1); A_STAGE(2, 2); SBAR0();              \
  WAITV(20);                                                        \
  B_CVTW(0, 0);                                                     \
  WAITL();                                                          \
  __builtin_amdgcn_s_barrier();                                     \
} while (0)

#define GEMM_MAIN(NT) do {                                          \
  for (int tb = 0; tb + 8 <= (NT); tb += 4) {                       \
    KSTEP_STD(tb + 0, 0); KSTEP_STD(tb + 1, 1);                     \
    KSTEP_STD(tb + 2, 2); KSTEP_STD(tb + 3, 3);                     \
  }                                                                 \
  KSTEP_STD((NT) - 4, 0);                                           \
  KSTEP_T3((NT) - 3, 1);                                            \
  KSTEP_T2(2);                                                      \
  KSTEP_LAST(3);                                                    \
} while (0)

// ---------------- GEMM1: h = relu(x @ W1[e] + b1[e]) for routed rows ----------------
__global__ __launch_bounds__(256) void k_gemm1(
    const bh* __restrict__ xbf, const float* __restrict__ W1,
    const float* __restrict__ b1, const int* __restrict__ tok_buck,
    const unsigned* __restrict__ cnt, const unsigned* __restrict__ offs,
    bh* __restrict__ hbf) {
  const int e = blockIdx.z, mt = blockIdx.y, nt = blockIdx.x;
  const int ne = (int)cnt[e];
  if (mt * 128 >= ne) return;
  __shared__ __align__(16) bh As[4][128 * 32];
  __shared__ __align__(16) bh Bs[4][128 * 32];
  const int tid = threadIdx.x;
  const int lane = tid & 63, wv = tid >> 6, wm = wv >> 1, wn_ = wv & 1;
  const int BRS = HDIM;  // W1 row stride over k(d)

  // A staging sources (gathered token rows, pre-swizzled)
  const bh* a_src[2]; int dst_off[2];
#pragma unroll
  for (int r = 0; r < 2; ++r) {
    int task = r * 256 + tid;
    int row = task >> 2, s = task & 3;
    int gm = mt * 128 + row; if (gm >= ne) gm = ne - 1;
    int tok = tok_buck[e * 1024 + gm];
    a_src[r] = xbf + (size_t)tok * 1024 + ((s ^ (row & 3)) << 3);
    dst_off[r] = (r * 256 + (wv << 6)) << 4;
  }
  // B staging source (native fp32 W1 [d][h])
  const int bcol = nt * 128 + (tid & 127);
  const int khalf = (tid >> 7) * 16;
  const int bq0 = (tid >> 7) * 2;
  const int bn8 = (tid & 127) * 8;
  const float* bsrc = W1 + (size_t)e * (DDIM * HDIM) + (size_t)khalf * BRS + bcol;
  float br[4][16];

  const int ln15 = lane & 15, q = lane >> 4;
  const int qs = ((q ^ (ln15 & 3)) << 3);
  int a_off[4];
#pragma unroll
  for (int i = 0; i < 4; ++i) a_off[i] = (wm * 64 + i * 16 + ln15) * 32 + qs;

  fx4 zero = {0.f, 0.f, 0.f, 0.f};
  fx4 acc[4][4];
#pragma unroll
  for (int i = 0; i < 4; ++i)
#pragma unroll
    for (int j = 0; j < 4; ++j) acc[i][j] = zero;

  GEMM_PROLOGUE();
  GEMM_MAIN(32);

  int nrows = ne - mt * 128; if (nrows > 128) nrows = 128;
  int jn[4]; float b1v[4];
#pragma unroll
  for (int j = 0; j < 4; ++j) {
    jn[j] = nt * 128 + wn_ * 64 + j * 16 + ln15;
    b1v[j] = b1[e * 2048 + jn[j]];
  }
  const int rowbase = (int)offs[e] + mt * 128;
#pragma unroll
  for (int i = 0; i < 4; ++i)
#pragma unroll
    for (int rr = 0; rr < 4; ++rr) {
      int ml = wm * 64 + i * 16 + q * 4 + rr;
      if (ml < nrows) {
        size_t ro = (size_t)(rowbase + ml) * 2048;
#pragma unroll
        for (int j = 0; j < 4; ++j) {
          float vv = acc[i][j][rr] + b1v[j];
          hbf[ro + jn[j]] = (bh)fmaxf(vv, 0.f);
        }
      }
    }
}

// ---------------- GEMM2: y += gate * exp(h @ W2[e] + b2[e]) ----------------
__global__ __launch_bounds__(256) void k_gemm2(
    const bh* __restrict__ hbf, const float* __restrict__ W2,
    const float* __restrict__ b2, const int* __restrict__ tok_buck,
    const float* __restrict__ gate_buck, const unsigned* __restrict__ cnt,
    const unsigned* __restrict__ offs, float* __restrict__ yv) {
  const int e = blockIdx.z, mt = blockIdx.y, nt = blockIdx.x;
  const int ne = (int)cnt[e];
  if (mt * 128 >= ne) return;
  __shared__ __align__(16) bh As[4][128 * 32];
  __shared__ __align__(16) bh Bs[4][128 * 32];
  const int tid = threadIdx.x;
  const int lane = tid & 63, wv = tid >> 6, wm = wv >> 1, wn_ = wv & 1;
  const int rowbase = (int)offs[e] + mt * 128;
  const int BRS = ODIM;  // W2 row stride over k(h)

  const bh* a_src[2]; int dst_off[2];
#pragma unroll
  for (int r = 0; r < 2; ++r) {
    int task = r * 256 + tid;
    int row = task >> 2, s = task & 3;
    a_src[r] = hbf + (size_t)(rowbase + row) * 2048 + ((s ^ (row & 3)) << 3);
    dst_off[r] = (r * 256 + (wv << 6)) << 4;
  }
  const int bcol = nt * 128 + (tid & 127);
  const int khalf = (tid >> 7) * 16;
  const int bq0 = (tid >> 7) * 2;
  const int bn8 = (tid & 127) * 8;
  const float* bsrc = W2 + (size_t)e * (HDIM * ODIM) + (size_t)khalf * BRS + bcol;
  float br[4][16];

  const int ln15 = lane & 15, q = lane >> 4;
  const int qs = ((q ^ (ln15 & 3)) << 3);
  int a_off[4];
#pragma unroll
  for (int i = 0; i < 4; ++i) a_off[i] = (wm * 64 + i * 16 + ln15) * 32 + qs;

  fx4 zero = {0.f, 0.f, 0.f, 0.f};
  fx4 acc[4][4];
#pragma unroll
  for (int i = 0; i < 4; ++i)
#pragma unroll
    for (int j = 0; j < 4; ++j) acc[i][j] = zero;

  GEMM_PROLOGUE();
  GEMM_MAIN(64);

  int nrows = ne - mt * 128; if (nrows > 128) nrows = 128;
  int on[4]; float b2v[4];
#pragma unroll
  for (int j = 0; j < 4; ++j) {
    on[j] = nt * 128 + wn_ * 64 + j * 16 + ln15;
    b2v[j] = b2[e * 1024 + on[j]];
  }
#pragma unroll
  for (int i = 0; i < 4; ++i)
#pragma unroll
    for (int rr = 0; rr < 4; ++rr) {
      int ml = wm * 64 + i * 16 + q * 4 + rr;
      if (ml < nrows) {
        int pos = mt * 128 + ml;
        int bt = tok_buck[e * 1024 + pos];
        float gg = gate_buck[e * 1024 + pos];
        float* yrow = yv + (size_t)bt * 1024;
#pragma unroll
        for (int j = 0; j < 4; ++j)
          atomicAdd(&yrow[on[j]], gg * expf(acc[i][j][rr] + b2v[j]));
      }
    }
}

// ---------------- final log ----------------
__global__ __launch_bounds__(256) void k_log(float* __restrict__ yv) {
  const int i = blockIdx.x * 256 + threadIdx.x;
  fx4* p = (fx4*)yv + i;
  fx4 v = *p;
#pragma unroll
  for (int c = 0; c < 4; ++c) {
    float w = v[c];
    if (w == 0.f) w = 2.2204460492503131e-16f;
    v[c] = logf(w);
  }
  *p = v;
}

extern "C" void kernel_launch(void* const* d_in, const int* in_sizes, int n_in,
                              void* d_out, int out_size, void* d_ws, size_t ws_size,
                              hipStream_t stream) {
  const float* x  = (const float*)d_in[0];
  const float* wg = (const float*)d_in[1];
  const float* wn = (const float*)d_in[2];
  const float* W1 = (const float*)d_in[3];
  const float* b1 = (const float*)d_in[4];
  const float* W2 = (const float*)d_in[5];
  const float* b2 = (const float*)d_in[6];
  const float* nz = (const float*)d_in[7];
  float* out = (float*)d_out;

  // workspace layout (bytes) — w1t/w2t eliminated (transpose fused into GEMMs)
  char* ws = (char*)d_ws;
  unsigned* cnt      = (unsigned*)(ws + 0);          // 64 B
  unsigned* offs     = (unsigned*)(ws + 64);         // 64 B
  float*    imp_part = (float*)(ws + 256);           // 64 KB
  float*    load_part= (float*)(ws + 256 + 65536);   // 64 KB
  int*      tok_buck = (int*)(ws + 256 + 2 * 65536); // 64 KB
  float*    gate_buck= (float*)(ws + 256 + 3 * 65536); // 64 KB
  bh*       xbf      = (bh*)(ws + 262400);           // 2 MB
  bh*       hbf      = (bh*)(ws + 2359552);          // (4096+128)*2048*2 = 16.5 MiB
  const size_t needed = 19661056;
  if (ws_size < needed) {
    // sentinel: distinguishable failure mode (absmax ~48) if ws is too small
    hipMemsetAsync(d_out, 0x42, (size_t)out_size * 4, stream);
    return;
  }

  hipMemsetAsync(d_out, 0, (size_t)out_size * 4, stream);
  hipMemsetAsync(cnt, 0, 64, stream);

  k_gating<<<1024, 256, 0, stream>>>(x, wg, wn, nz, xbf, cnt, tok_buck, gate_buck,
                                     imp_part, load_part);
  k_finalize<<<1, 256, 0, stream>>>(cnt, offs, imp_part, load_part, out + (out_size - 1));
  k_gemm1<<<dim3(16, 8, 16), 256, 0, stream>>>(xbf, W1, b1, tok_buck, cnt, offs, hbf);
  k_gemm2<<<dim3(8, 8, 16), 256, 0, stream>>>(hbf, W2, b2, tok_buck, gate_buck, cnt, offs, out);
  k_log<<<1024, 256, 0, stream>>>(out);
}